// Round 2
// baseline (491.618 us; speedup 1.0000x reference)
//
#include <hip/hip_runtime.h>
#include <stdint.h>

typedef unsigned short u16;
typedef short bf16x8 __attribute__((ext_vector_type(8)));
typedef float f32x4 __attribute__((ext_vector_type(4)));

#define B_   2
#define L_   2048
#define DIM_ 2048
#define H_   16
#define D_   128
#define E3_  6144
#define ML_  4096   // B_*L_

__device__ __forceinline__ u16 f2b(float f) {
  union { float f; unsigned u; } v; v.f = f;
  return (u16)((v.u + 0x7FFFu + ((v.u >> 16) & 1u)) >> 16);
}
__device__ __forceinline__ float b2f(u16 h) {
  union { unsigned u; float f; } v; v.u = ((unsigned)h) << 16; return v.f;
}

__device__ __forceinline__ void gl_lds16(const void* g, void* l) {
  __builtin_amdgcn_global_load_lds((const __attribute__((address_space(1))) void*)g,
                                   (__attribute__((address_space(3))) void*)l, 16, 0, 0);
}

// ---------------- f32 -> bf16 convert ----------------
__global__ __launch_bounds__(256) void cvt_kernel(const float* __restrict__ in,
                                                  u16* __restrict__ out, int n4) {
  int i = blockIdx.x * 256 + threadIdx.x;
  int stride = gridDim.x * 256;
  for (; i < n4; i += stride) {
    float4 v = reinterpret_cast<const float4*>(in)[i];
    ushort4 o = make_ushort4(f2b(v.x), f2b(v.y), f2b(v.z), f2b(v.w));
    reinterpret_cast<ushort4*>(out)[i] = o;
  }
}

// ---------------- GEMM: C[M][N] = A[M][K] * Bm[N][K]^T ----------------
template<int OUTF32>
__global__ __launch_bounds__(256, 2) void gemm_bt(
    const u16* __restrict__ A, const u16* __restrict__ Bm,
    u16* __restrict__ Cb, float* __restrict__ Cf, const float* __restrict__ bias,
    int M, int N, int K) {
  __shared__ __align__(16) u16 As[128 * 32];
  __shared__ __align__(16) u16 Bs[128 * 32];
  const int tid = threadIdx.x;
  const int w = tid >> 6;
  const int g = (tid >> 4) & 3, r = tid & 15;
  const int wr = w >> 1, wc = w & 1;
  const long row0 = (long)blockIdx.y * 128, col0 = (long)blockIdx.x * 128;

  const f32x4 fz = {0.f, 0.f, 0.f, 0.f};
  f32x4 acc[4][4];
#pragma unroll
  for (int m = 0; m < 4; ++m)
#pragma unroll
    for (int n = 0; n < 4; ++n) acc[m][n] = fz;

  for (int k0 = 0; k0 < K; k0 += 32) {
#pragma unroll
    for (int it = 0; it < 2; ++it) {
      int c = it * 256 + tid;
      gl_lds16(A + (row0 + (c >> 2)) * (long)K + k0 + ((c & 3) << 3),
               (char*)As + ((it * 256 + (w << 6)) << 4));
      gl_lds16(Bm + (col0 + (c >> 2)) * (long)K + k0 + ((c & 3) << 3),
               (char*)Bs + ((it * 256 + (w << 6)) << 4));
    }
    __syncthreads();
    bf16x8 af[4], bfr[4];
#pragma unroll
    for (int m = 0; m < 4; ++m)
      af[m] = *reinterpret_cast<const bf16x8*>(As + (wr * 64 + m * 16 + r) * 32 + g * 8);
#pragma unroll
    for (int n = 0; n < 4; ++n)
      bfr[n] = *reinterpret_cast<const bf16x8*>(Bs + (wc * 64 + n * 16 + r) * 32 + g * 8);
#pragma unroll
    for (int m = 0; m < 4; ++m)
#pragma unroll
      for (int n = 0; n < 4; ++n)
        acc[m][n] = __builtin_amdgcn_mfma_f32_16x16x32_bf16(af[m], bfr[n], acc[m][n], 0, 0, 0);
    __syncthreads();
  }

#pragma unroll
  for (int m = 0; m < 4; ++m)
#pragma unroll
    for (int n = 0; n < 4; ++n)
#pragma unroll
      for (int j = 0; j < 4; ++j) {
        long rr = row0 + wr * 64 + m * 16 + g * 4 + j;
        long cc = col0 + wc * 64 + n * 16 + r;
        if constexpr (OUTF32) {
          Cf[rr * N + cc] = acc[m][n][j] + bias[cc];
        } else {
          Cb[rr * N + cc] = f2b(acc[m][n][j]);
        }
      }
}

// ---------------- RMSNorm + RoPE for q,k; scatter to [B,H,L,D] ----------------
__global__ __launch_bounds__(256) void normrope_kernel(
    const u16* __restrict__ qkv, const float* __restrict__ pe,
    const float* __restrict__ qsc, const float* __restrict__ ksc,
    u16* __restrict__ Qo, u16* __restrict__ Ko) {
  const int w = threadIdx.x >> 6, ln = threadIdx.x & 63;
  const int idx = blockIdx.x * 4 + w;          // (b*L + l)*16 + h
  const int h = idx & 15, bl = idx >> 4;
  const int l = bl & (L_ - 1), b = bl >> 11;
  const u16* base = qkv + (long)bl * E3_ + h * D_;
  const float4 pv = *reinterpret_cast<const float4*>(pe + ((long)l * 64 + ln) * 4);
  const long obase = (((long)(b * H_ + h)) * L_ + l) * D_ + 2 * ln;
  // q
  {
    unsigned qv = *reinterpret_cast<const unsigned*>(base + 2 * ln);
    float x0 = b2f((u16)qv), x1 = b2f((u16)(qv >> 16));
    float ss = x0 * x0 + x1 * x1;
#pragma unroll
    for (int msk = 1; msk < 64; msk <<= 1) ss += __shfl_xor(ss, msk);
    float rr = rsqrtf(ss * (1.0f / 128.0f) + 1e-6f);
    float y0 = x0 * rr * qsc[2 * ln], y1 = x1 * rr * qsc[2 * ln + 1];
    float o0 = pv.x * y0 + pv.y * y1, o1 = pv.z * y0 + pv.w * y1;
    *reinterpret_cast<unsigned*>(Qo + obase) = (unsigned)f2b(o0) | ((unsigned)f2b(o1) << 16);
  }
  // k
  {
    unsigned kv = *reinterpret_cast<const unsigned*>(base + DIM_ + 2 * ln);
    float x0 = b2f((u16)kv), x1 = b2f((u16)(kv >> 16));
    float ss = x0 * x0 + x1 * x1;
#pragma unroll
    for (int msk = 1; msk < 64; msk <<= 1) ss += __shfl_xor(ss, msk);
    float rr = rsqrtf(ss * (1.0f / 128.0f) + 1e-6f);
    float y0 = x0 * rr * ksc[2 * ln], y1 = x1 * rr * ksc[2 * ln + 1];
    float o0 = pv.x * y0 + pv.y * y1, o1 = pv.z * y0 + pv.w * y1;
    *reinterpret_cast<unsigned*>(Ko + obase) = (unsigned)f2b(o0) | ((unsigned)f2b(o1) << 16);
  }
}

// ---------------- V transpose: qkv v-part -> VT[B,H,D,L] ----------------
__global__ __launch_bounds__(256) void vtrans_kernel(const u16* __restrict__ qkv,
                                                     u16* __restrict__ VT) {
  __shared__ u16 t[64][132];
  const int tid = threadIdx.x;
  const int bh = blockIdx.x >> 5, lt = blockIdx.x & 31;
  const int b = bh >> 4, h = bh & 15;
  const int l0 = lt << 6;
  const u16* src = qkv + ((long)(b * L_ + l0)) * E3_ + 2 * DIM_ + h * D_;
#pragma unroll
  for (int i = 0; i < 32; ++i) {
    int o = i * 256 + tid;
    int lr = o >> 7, d = o & 127;
    t[lr][d] = src[(long)lr * E3_ + d];
  }
  __syncthreads();
  u16* dst = VT + (long)bh * (D_ * L_) + l0;
#pragma unroll
  for (int i = 0; i < 32; ++i) {
    int o = i * 256 + tid;
    int d = o >> 6, lr = o & 63;
    dst[(long)d * L_ + lr] = t[lr][d];
  }
}

// ---------------- Flash attention ----------------
__global__ __launch_bounds__(256, 2) void flash_kernel(
    const u16* __restrict__ Qg, const u16* __restrict__ Kg,
    const u16* __restrict__ Vt, u16* __restrict__ Og) {
  __shared__ __align__(16) u16 Ks[64 * 128];   // [kk][d]   swizzled rows of 256B
  __shared__ __align__(16) u16 Vs[128 * 64];   // [d][kk]   swizzled rows of 128B
  __shared__ __align__(16) u16 Ps[128 * 64];   // [q][kk]   swizzled rows of 128B
  const int tid = threadIdx.x, w = tid >> 6;
  const int g = (tid >> 4) & 3, r = tid & 15;
  const int bh = blockIdx.y, q0 = blockIdx.x * 128;
  const int b = bh >> 4, h = bh & 15;
  const u16* Qb = Qg + (long)bh * (L_ * D_);
  const u16* Kb = Kg + (long)bh * (L_ * D_);
  const u16* Vb = Vt + (long)bh * (L_ * D_);   // [128][2048]
  char* KsB = (char*)Ks; char* VsB = (char*)Vs; char* PsB = (char*)Ps;
  const float sc = 0.08838834764831845f;       // 1/sqrt(128)

  bf16x8 qf[2][4];
#pragma unroll
  for (int m = 0; m < 2; ++m)
#pragma unroll
    for (int t = 0; t < 4; ++t)
      qf[m][t] = *reinterpret_cast<const bf16x8*>(
          Qb + (long)(q0 + w * 32 + m * 16 + r) * D_ + t * 32 + g * 8);

  const f32x4 fz = {0.f, 0.f, 0.f, 0.f};
  f32x4 oacc[2][8];
  f32x4 mrun[2], lrun[2];
#pragma unroll
  for (int m = 0; m < 2; ++m) {
    mrun[m] = (f32x4){-3.0e38f, -3.0e38f, -3.0e38f, -3.0e38f};
    lrun[m] = fz;
#pragma unroll
    for (int n = 0; n < 8; ++n) oacc[m][n] = fz;
  }

  for (int kt = 0; kt < 32; ++kt) {
    const int kk0 = kt * 64;
    const u16* Ksrc = Kb + (long)kk0 * D_;
#pragma unroll
    for (int it = 0; it < 4; ++it) {
      int c = it * 256 + tid;
      int pb = c << 4;
      int krow = pb >> 8;
      int klb = (pb & 255) ^ ((krow & 7) << 4);
      gl_lds16(Ksrc + (long)krow * D_ + (klb >> 1), KsB + ((it * 256 + (w << 6)) << 4));
      int vrow = pb >> 7;
      int vlb = (pb & 127) ^ ((vrow & 7) << 4);
      gl_lds16(Vb + (long)vrow * L_ + kk0 + (vlb >> 1), VsB + ((it * 256 + (w << 6)) << 4));
    }
    __syncthreads();

    // S = Q K^T  (per wave: 32 q rows x 64 kk)
    f32x4 s[2][4];
#pragma unroll
    for (int m = 0; m < 2; ++m)
#pragma unroll
      for (int n = 0; n < 4; ++n) s[m][n] = fz;
#pragma unroll
    for (int t = 0; t < 4; ++t) {
#pragma unroll
      for (int n = 0; n < 4; ++n) {
        int kr = n * 16 + r;
        bf16x8 kf = *reinterpret_cast<const bf16x8*>(
            KsB + ((kr << 8) | ((t * 64 + g * 16) ^ ((kr & 7) << 4))));
#pragma unroll
        for (int m = 0; m < 2; ++m)
          s[m][n] = __builtin_amdgcn_mfma_f32_16x16x32_bf16(qf[m][t], kf, s[m][n], 0, 0, 0);
      }
    }

    // online softmax (scaled domain)
#pragma unroll
    for (int m = 0; m < 2; ++m) {
      f32x4 rmx = s[m][0];
#pragma unroll
      for (int n = 1; n < 4; ++n)
#pragma unroll
        for (int j = 0; j < 4; ++j) rmx[j] = fmaxf(rmx[j], s[m][n][j]);
#pragma unroll
      for (int j = 0; j < 4; ++j) {
#pragma unroll
        for (int msk = 1; msk < 16; msk <<= 1)
          rmx[j] = fmaxf(rmx[j], __shfl_xor(rmx[j], msk));
      }
      f32x4 mnew, corr, rsum;
#pragma unroll
      for (int j = 0; j < 4; ++j) {
        mnew[j] = fmaxf(mrun[m][j], rmx[j] * sc);
        corr[j] = __expf(mrun[m][j] - mnew[j]);
        rsum[j] = 0.f;
      }
#pragma unroll
      for (int n = 0; n < 4; ++n) {
#pragma unroll
        for (int j = 0; j < 4; ++j) {
          float p = __expf(s[m][n][j] * sc - mnew[j]);
          rsum[j] += p;
          int ql = w * 32 + m * 16 + g * 4 + j;
          int col = n * 16 + r;
          *reinterpret_cast<u16*>(PsB + ((ql << 7) | ((col << 1) ^ ((ql & 7) << 4)))) = f2b(p);
        }
      }
#pragma unroll
      for (int j = 0; j < 4; ++j) {
#pragma unroll
        for (int msk = 1; msk < 16; msk <<= 1) rsum[j] += __shfl_xor(rsum[j], msk);
        lrun[m][j] = lrun[m][j] * corr[j] + rsum[j];
      }
      mrun[m] = mnew;
#pragma unroll
      for (int n = 0; n < 8; ++n)
#pragma unroll
        for (int j = 0; j < 4; ++j) oacc[m][n][j] *= corr[j];
    }

    // O += P V  (A = P from LDS, B = VT from LDS)
#pragma unroll
    for (int t = 0; t < 2; ++t) {
      bf16x8 pf[2];
#pragma unroll
      for (int m = 0; m < 2; ++m) {
        int pr = w * 32 + m * 16 + r;
        pf[m] = *reinterpret_cast<const bf16x8*>(
            PsB + ((pr << 7) | ((t * 64 + g * 16) ^ ((pr & 7) << 4))));
      }
#pragma unroll
      for (int n = 0; n < 8; ++n) {
        int vr = n * 16 + r;
        bf16x8 vf = *reinterpret_cast<const bf16x8*>(
            VsB + ((vr << 7) | ((t * 64 + g * 16) ^ ((vr & 7) << 4))));
#pragma unroll
        for (int m = 0; m < 2; ++m)
          oacc[m][n] = __builtin_amdgcn_mfma_f32_16x16x32_bf16(pf[m], vf, oacc[m][n], 0, 0, 0);
      }
    }
    __syncthreads();
  }

  // epilogue: O /= l, write [B, L, H*D]
#pragma unroll
  for (int m = 0; m < 2; ++m) {
    f32x4 inv;
#pragma unroll
    for (int j = 0; j < 4; ++j) inv[j] = 1.0f / lrun[m][j];
#pragma unroll
    for (int n = 0; n < 8; ++n)
#pragma unroll
      for (int j = 0; j < 4; ++j) {
        int ql = w * 32 + m * 16 + g * 4 + j;
        int col = n * 16 + r;
        Og[((long)(b * L_) + q0 + ql) * DIM_ + h * D_ + col] = f2b(oacc[m][n][j] * inv[j]);
      }
  }
}

extern "C" void kernel_launch(void* const* d_in, const int* in_sizes, int n_in,
                              void* d_out, int out_size, void* d_ws, size_t ws_size,
                              hipStream_t stream) {
  const float* x    = (const float*)d_in[0];
  const float* pe   = (const float*)d_in[1];
  const float* qkvw = (const float*)d_in[2];
  const float* qsc  = (const float*)d_in[3];
  const float* ksc  = (const float*)d_in[4];
  const float* pw   = (const float*)d_in[5];
  const float* pb   = (const float*)d_in[6];
  float* out = (float*)d_out;

  u16* ws_x   = (u16*)d_ws;                   //  8,388,608 elems
  u16* ws_w1  = ws_x   + (size_t)ML_ * DIM_;  // 12,582,912
  u16* ws_w2  = ws_w1  + (size_t)E3_ * DIM_;  //  4,194,304
  u16* ws_qkv = ws_w2  + (size_t)DIM_ * DIM_; // 25,165,824
  u16* ws_q   = ws_qkv + (size_t)ML_ * E3_;   //  8,388,608
  u16* ws_k   = ws_q   + (size_t)ML_ * DIM_;
  u16* ws_vt  = ws_k   + (size_t)ML_ * DIM_;
  u16* ws_o   = ws_vt  + (size_t)ML_ * DIM_;  // total 160 MiB

  cvt_kernel<<<2048, 256, 0, stream>>>(x, ws_x, ML_ * DIM_ / 4);
  cvt_kernel<<<2048, 256, 0, stream>>>(qkvw, ws_w1, E3_ * DIM_ / 4);
  cvt_kernel<<<2048, 256, 0, stream>>>(pw, ws_w2, DIM_ * DIM_ / 4);

  gemm_bt<0><<<dim3(E3_ / 128, ML_ / 128), 256, 0, stream>>>(
      ws_x, ws_w1, ws_qkv, nullptr, nullptr, ML_, E3_, DIM_);
  normrope_kernel<<<(B_ * L_ * H_) / 4, 256, 0, stream>>>(ws_qkv, pe, qsc, ksc, ws_q, ws_k);
  vtrans_kernel<<<B_ * H_ * (L_ / 64), 256, 0, stream>>>(ws_qkv, ws_vt);
  flash_kernel<<<dim3(L_ / 128, B_ * H_), 256, 0, stream>>>(ws_q, ws_k, ws_vt, ws_o);
  gemm_bt<1><<<dim3(DIM_ / 128, ML_ / 128), 256, 0, stream>>>(
      ws_o, ws_w2, nullptr, out, pb, ML_, DIM_, DIM_);
}

// Round 3
// 483.066 us; speedup vs baseline: 1.0177x; 1.0177x over previous
//
#include <hip/hip_runtime.h>
#include <stdint.h>

typedef unsigned short u16;
typedef short bf16x8 __attribute__((ext_vector_type(8)));
typedef float f32x4 __attribute__((ext_vector_type(4)));

#define B_   2
#define L_   2048
#define DIM_ 2048
#define H_   16
#define D_   128
#define E3_  6144
#define ML_  4096   // B_*L_

__device__ __forceinline__ u16 f2b(float f) {
  union { float f; unsigned u; } v; v.f = f;
  return (u16)((v.u + 0x7FFFu + ((v.u >> 16) & 1u)) >> 16);
}
__device__ __forceinline__ float b2f(u16 h) {
  union { unsigned u; float f; } v; v.u = ((unsigned)h) << 16; return v.f;
}

__device__ __forceinline__ void gl_lds16(const void* g, void* l) {
  __builtin_amdgcn_global_load_lds((const __attribute__((address_space(1))) void*)g,
                                   (__attribute__((address_space(3))) void*)l, 16, 0, 0);
}

// ---------------- f32 -> bf16 convert ----------------
__global__ __launch_bounds__(256) void cvt_kernel(const float* __restrict__ in,
                                                  u16* __restrict__ out, int n4) {
  int i = blockIdx.x * 256 + threadIdx.x;
  int stride = gridDim.x * 256;
  for (; i < n4; i += stride) {
    float4 v = reinterpret_cast<const float4*>(in)[i];
    ushort4 o = make_ushort4(f2b(v.x), f2b(v.y), f2b(v.z), f2b(v.w));
    reinterpret_cast<ushort4*>(out)[i] = o;
  }
}

// ---------------- GEMM: C[M][N] = A[M][K] * Bm[N][K]^T ----------------
template<int OUTF32>
__global__ __launch_bounds__(256, 2) void gemm_bt(
    const u16* __restrict__ A, const u16* __restrict__ Bm,
    u16* __restrict__ Cb, float* __restrict__ Cf, const float* __restrict__ bias,
    int M, int N, int K) {
  __shared__ __align__(16) u16 As[128 * 32];
  __shared__ __align__(16) u16 Bs[128 * 32];
  const int tid = threadIdx.x;
  const int w = tid >> 6;
  const int g = (tid >> 4) & 3, r = tid & 15;
  const int wr = w >> 1, wc = w & 1;
  const long row0 = (long)blockIdx.y * 128, col0 = (long)blockIdx.x * 128;

  const f32x4 fz = {0.f, 0.f, 0.f, 0.f};
  f32x4 acc[4][4];
#pragma unroll
  for (int m = 0; m < 4; ++m)
#pragma unroll
    for (int n = 0; n < 4; ++n) acc[m][n] = fz;

  for (int k0 = 0; k0 < K; k0 += 32) {
#pragma unroll
    for (int it = 0; it < 2; ++it) {
      int c = it * 256 + tid;
      gl_lds16(A + (row0 + (c >> 2)) * (long)K + k0 + ((c & 3) << 3),
               (char*)As + ((it * 256 + (w << 6)) << 4));
      gl_lds16(Bm + (col0 + (c >> 2)) * (long)K + k0 + ((c & 3) << 3),
               (char*)Bs + ((it * 256 + (w << 6)) << 4));
    }
    __syncthreads();
    bf16x8 af[4], bfr[4];
#pragma unroll
    for (int m = 0; m < 4; ++m)
      af[m] = *reinterpret_cast<const bf16x8*>(As + (wr * 64 + m * 16 + r) * 32 + g * 8);
#pragma unroll
    for (int n = 0; n < 4; ++n)
      bfr[n] = *reinterpret_cast<const bf16x8*>(Bs + (wc * 64 + n * 16 + r) * 32 + g * 8);
#pragma unroll
    for (int m = 0; m < 4; ++m)
#pragma unroll
      for (int n = 0; n < 4; ++n)
        acc[m][n] = __builtin_amdgcn_mfma_f32_16x16x32_bf16(af[m], bfr[n], acc[m][n], 0, 0, 0);
    __syncthreads();
  }

#pragma unroll
  for (int m = 0; m < 4; ++m)
#pragma unroll
    for (int n = 0; n < 4; ++n)
#pragma unroll
      for (int j = 0; j < 4; ++j) {
        long rr = row0 + wr * 64 + m * 16 + g * 4 + j;
        long cc = col0 + wc * 64 + n * 16 + r;
        if constexpr (OUTF32) {
          Cf[rr * N + cc] = acc[m][n][j] + bias[cc];
        } else {
          Cb[rr * N + cc] = f2b(acc[m][n][j]);
        }
      }
}

// ---------------- RMSNorm + RoPE for q,k; scatter to [B,H,L,D] ----------------
__global__ __launch_bounds__(256) void normrope_kernel(
    const u16* __restrict__ qkv, const float* __restrict__ pe,
    const float* __restrict__ qsc, const float* __restrict__ ksc,
    u16* __restrict__ Qo, u16* __restrict__ Ko) {
  const int w = threadIdx.x >> 6, ln = threadIdx.x & 63;
  const int idx = blockIdx.x * 4 + w;          // (b*L + l)*16 + h
  const int h = idx & 15, bl = idx >> 4;
  const int l = bl & (L_ - 1), b = bl >> 11;
  const u16* base = qkv + (long)bl * E3_ + h * D_;
  const float4 pv = *reinterpret_cast<const float4*>(pe + ((long)l * 64 + ln) * 4);
  const long obase = (((long)(b * H_ + h)) * L_ + l) * D_ + 2 * ln;
  // q
  {
    unsigned qv = *reinterpret_cast<const unsigned*>(base + 2 * ln);
    float x0 = b2f((u16)qv), x1 = b2f((u16)(qv >> 16));
    float ss = x0 * x0 + x1 * x1;
#pragma unroll
    for (int msk = 1; msk < 64; msk <<= 1) ss += __shfl_xor(ss, msk);
    float rr = rsqrtf(ss * (1.0f / 128.0f) + 1e-6f);
    float y0 = x0 * rr * qsc[2 * ln], y1 = x1 * rr * qsc[2 * ln + 1];
    float o0 = pv.x * y0 + pv.y * y1, o1 = pv.z * y0 + pv.w * y1;
    *reinterpret_cast<unsigned*>(Qo + obase) = (unsigned)f2b(o0) | ((unsigned)f2b(o1) << 16);
  }
  // k
  {
    unsigned kv = *reinterpret_cast<const unsigned*>(base + DIM_ + 2 * ln);
    float x0 = b2f((u16)kv), x1 = b2f((u16)(kv >> 16));
    float ss = x0 * x0 + x1 * x1;
#pragma unroll
    for (int msk = 1; msk < 64; msk <<= 1) ss += __shfl_xor(ss, msk);
    float rr = rsqrtf(ss * (1.0f / 128.0f) + 1e-6f);
    float y0 = x0 * rr * ksc[2 * ln], y1 = x1 * rr * ksc[2 * ln + 1];
    float o0 = pv.x * y0 + pv.y * y1, o1 = pv.z * y0 + pv.w * y1;
    *reinterpret_cast<unsigned*>(Ko + obase) = (unsigned)f2b(o0) | ((unsigned)f2b(o1) << 16);
  }
}

// ---------------- V transpose: qkv v-part -> VT[B,H,D,L] ----------------
__global__ __launch_bounds__(256) void vtrans_kernel(const u16* __restrict__ qkv,
                                                     u16* __restrict__ VT) {
  __shared__ u16 t[64][132];
  const int tid = threadIdx.x;
  const int bh = blockIdx.x >> 5, lt = blockIdx.x & 31;
  const int b = bh >> 4, h = bh & 15;
  const int l0 = lt << 6;
  const u16* src = qkv + ((long)(b * L_ + l0)) * E3_ + 2 * DIM_ + h * D_;
#pragma unroll
  for (int i = 0; i < 32; ++i) {
    int o = i * 256 + tid;
    int lr = o >> 7, d = o & 127;
    t[lr][d] = src[(long)lr * E3_ + d];
  }
  __syncthreads();
  u16* dst = VT + (long)bh * (D_ * L_) + l0;
#pragma unroll
  for (int i = 0; i < 32; ++i) {
    int o = i * 256 + tid;
    int d = o >> 6, lr = o & 63;
    dst[(long)d * L_ + lr] = t[lr][d];
  }
}

// ---------------- Flash attention (2-phase dbuf pipeline) ----------------
__global__ __launch_bounds__(256, 2) void flash_kernel(
    const u16* __restrict__ Qg, const u16* __restrict__ Kg,
    const u16* __restrict__ Vt, u16* __restrict__ Og) {
  __shared__ __align__(16) u16 Ks[2][64 * 128];   // [kk][d]   swizzled rows of 256B
  __shared__ __align__(16) u16 Vs[2][128 * 64];   // [d][kk]   swizzled rows of 128B
  __shared__ __align__(16) u16 Ps[128 * 64];      // [q][kk]   swizzled rows of 128B
  const int tid = threadIdx.x, w = tid >> 6;
  const int g = (tid >> 4) & 3, r = tid & 15;
  const int bh = blockIdx.y, q0 = blockIdx.x * 128;
  const int b = bh >> 4, h = bh & 15;
  const u16* Qb = Qg + (long)bh * (L_ * D_);
  const u16* Kb = Kg + (long)bh * (L_ * D_);
  const u16* Vb = Vt + (long)bh * (L_ * D_);   // [128][2048]
  char* PsB = (char*)Ps;
  const float sc = 0.08838834764831845f;       // 1/sqrt(128)

  bf16x8 qf[2][4];
#pragma unroll
  for (int m = 0; m < 2; ++m)
#pragma unroll
    for (int t = 0; t < 4; ++t)
      qf[m][t] = *reinterpret_cast<const bf16x8*>(
          Qb + (long)(q0 + w * 32 + m * 16 + r) * D_ + t * 32 + g * 8);

  const f32x4 fz = {0.f, 0.f, 0.f, 0.f};
  f32x4 oacc[2][8];
  f32x4 mrun[2], lrun[2];
#pragma unroll
  for (int m = 0; m < 2; ++m) {
    mrun[m] = (f32x4){-3.0e38f, -3.0e38f, -3.0e38f, -3.0e38f};
    lrun[m] = fz;
#pragma unroll
    for (int n = 0; n < 8; ++n) oacc[m][n] = fz;
  }

  // stage K/V tile kt into buffer buf
  auto stage = [&](int buf, int kt) {
    const int kk0 = kt * 64;
    const u16* Ksrc = Kb + (long)kk0 * D_;
    char* KsB = (char*)Ks[buf];
    char* VsB = (char*)Vs[buf];
#pragma unroll
    for (int it = 0; it < 4; ++it) {
      int c = it * 256 + tid;
      int pb = c << 4;
      int krow = pb >> 8;
      int klb = (pb & 255) ^ ((krow & 7) << 4);
      gl_lds16(Ksrc + (long)krow * D_ + (klb >> 1), KsB + ((it * 256 + (w << 6)) << 4));
      int vrow = pb >> 7;
      int vlb = (pb & 127) ^ ((vrow & 7) << 4);
      gl_lds16(Vb + (long)vrow * L_ + kk0 + (vlb >> 1), VsB + ((it * 256 + (w << 6)) << 4));
    }
  };

  // prologue: fill buffer 0
  stage(0, 0);
  asm volatile("s_waitcnt vmcnt(0)" ::: "memory");
  __builtin_amdgcn_s_barrier();

  for (int kt = 0; kt < 32; ++kt) {
    const int cur = kt & 1;
    if (kt + 1 < 32) stage(cur ^ 1, kt + 1);   // prefetch next tile (in flight across compute)
    const char* KsB = (const char*)Ks[cur];
    const char* VsB = (const char*)Vs[cur];

    // S = Q K^T  (per wave: 32 q rows x 64 kk)
    f32x4 s[2][4];
#pragma unroll
    for (int m = 0; m < 2; ++m)
#pragma unroll
      for (int n = 0; n < 4; ++n) s[m][n] = fz;
    __builtin_amdgcn_s_setprio(1);
#pragma unroll
    for (int t = 0; t < 4; ++t) {
#pragma unroll
      for (int n = 0; n < 4; ++n) {
        int kr = n * 16 + r;
        bf16x8 kf = *reinterpret_cast<const bf16x8*>(
            KsB + ((kr << 8) | ((t * 64 + g * 16) ^ ((kr & 7) << 4))));
#pragma unroll
        for (int m = 0; m < 2; ++m)
          s[m][n] = __builtin_amdgcn_mfma_f32_16x16x32_bf16(qf[m][t], kf, s[m][n], 0, 0, 0);
      }
    }
    __builtin_amdgcn_s_setprio(0);

    // online softmax (scaled domain), T13 defer-max
#pragma unroll
    for (int m = 0; m < 2; ++m) {
      f32x4 rmx = s[m][0];
#pragma unroll
      for (int n = 1; n < 4; ++n)
#pragma unroll
        for (int j = 0; j < 4; ++j) rmx[j] = fmaxf(rmx[j], s[m][n][j]);
#pragma unroll
      for (int j = 0; j < 4; ++j) {
#pragma unroll
        for (int msk = 1; msk < 16; msk <<= 1)
          rmx[j] = fmaxf(rmx[j], __shfl_xor(rmx[j], msk));
      }
      float growth = rmx[0] * sc - mrun[m][0];
#pragma unroll
      for (int j = 1; j < 4; ++j) growth = fmaxf(growth, rmx[j] * sc - mrun[m][j]);
      if (!__all(growth <= 8.0f)) {
#pragma unroll
        for (int j = 0; j < 4; ++j) {
          float mnew = fmaxf(mrun[m][j], rmx[j] * sc);
          float corr = __expf(mrun[m][j] - mnew);
          mrun[m][j] = mnew;
          lrun[m][j] *= corr;
#pragma unroll
          for (int n = 0; n < 8; ++n) oacc[m][n][j] *= corr;
        }
      }
      f32x4 rsum = fz;
#pragma unroll
      for (int n = 0; n < 4; ++n) {
#pragma unroll
        for (int j = 0; j < 4; ++j) {
          float p = __expf(s[m][n][j] * sc - mrun[m][j]);
          rsum[j] += p;
          int ql = w * 32 + m * 16 + g * 4 + j;
          int col = n * 16 + r;
          *reinterpret_cast<u16*>(PsB + ((ql << 7) | ((col << 1) ^ ((ql & 7) << 4)))) = f2b(p);
        }
      }
#pragma unroll
      for (int j = 0; j < 4; ++j) {
#pragma unroll
        for (int msk = 1; msk < 16; msk <<= 1) rsum[j] += __shfl_xor(rsum[j], msk);
        lrun[m][j] += rsum[j];
      }
    }

    // O += P V  (A = P from LDS, B = VT from LDS)
    __builtin_amdgcn_s_setprio(1);
#pragma unroll
    for (int t = 0; t < 2; ++t) {
      bf16x8 pf[2];
#pragma unroll
      for (int m = 0; m < 2; ++m) {
        int pr = w * 32 + m * 16 + r;
        pf[m] = *reinterpret_cast<const bf16x8*>(
            PsB + ((pr << 7) | ((t * 64 + g * 16) ^ ((pr & 7) << 4))));
      }
#pragma unroll
      for (int n = 0; n < 8; ++n) {
        int vr = n * 16 + r;
        bf16x8 vf = *reinterpret_cast<const bf16x8*>(
            VsB + ((vr << 7) | ((t * 64 + g * 16) ^ ((vr & 7) << 4))));
#pragma unroll
        for (int m = 0; m < 2; ++m)
          oacc[m][n] = __builtin_amdgcn_mfma_f32_16x16x32_bf16(pf[m], vf, oacc[m][n], 0, 0, 0);
      }
    }
    __builtin_amdgcn_s_setprio(0);

    // end of iter: next tile's loads complete; all waves done with buf[cur]
    asm volatile("s_waitcnt vmcnt(0)" ::: "memory");
    __builtin_amdgcn_s_barrier();
  }

  // epilogue: O /= l, write [B, L, H*D]
#pragma unroll
  for (int m = 0; m < 2; ++m) {
    f32x4 inv;
#pragma unroll
    for (int j = 0; j < 4; ++j) inv[j] = 1.0f / lrun[m][j];
#pragma unroll
    for (int n = 0; n < 8; ++n)
#pragma unroll
      for (int j = 0; j < 4; ++j) {
        int ql = w * 32 + m * 16 + g * 4 + j;
        int col = n * 16 + r;
        Og[((long)(b * L_) + q0 + ql) * DIM_ + h * D_ + col] = f2b(oacc[m][n][j] * inv[j]);
      }
  }
}

extern "C" void kernel_launch(void* const* d_in, const int* in_sizes, int n_in,
                              void* d_out, int out_size, void* d_ws, size_t ws_size,
                              hipStream_t stream) {
  const float* x    = (const float*)d_in[0];
  const float* pe   = (const float*)d_in[1];
  const float* qkvw = (const float*)d_in[2];
  const float* qsc  = (const float*)d_in[3];
  const float* ksc  = (const float*)d_in[4];
  const float* pw   = (const float*)d_in[5];
  const float* pb   = (const float*)d_in[6];
  float* out = (float*)d_out;

  u16* ws_x   = (u16*)d_ws;                   //  8,388,608 elems
  u16* ws_w1  = ws_x   + (size_t)ML_ * DIM_;  // 12,582,912
  u16* ws_w2  = ws_w1  + (size_t)E3_ * DIM_;  //  4,194,304
  u16* ws_qkv = ws_w2  + (size_t)DIM_ * DIM_; // 25,165,824
  u16* ws_q   = ws_qkv + (size_t)ML_ * E3_;   //  8,388,608
  u16* ws_k   = ws_q   + (size_t)ML_ * DIM_;
  u16* ws_vt  = ws_k   + (size_t)ML_ * DIM_;
  u16* ws_o   = ws_vt  + (size_t)ML_ * DIM_;  // total 160 MiB

  cvt_kernel<<<2048, 256, 0, stream>>>(x, ws_x, ML_ * DIM_ / 4);
  cvt_kernel<<<2048, 256, 0, stream>>>(qkvw, ws_w1, E3_ * DIM_ / 4);
  cvt_kernel<<<2048, 256, 0, stream>>>(pw, ws_w2, DIM_ * DIM_ / 4);

  gemm_bt<0><<<dim3(E3_ / 128, ML_ / 128), 256, 0, stream>>>(
      ws_x, ws_w1, ws_qkv, nullptr, nullptr, ML_, E3_, DIM_);
  normrope_kernel<<<(B_ * L_ * H_) / 4, 256, 0, stream>>>(ws_qkv, pe, qsc, ksc, ws_q, ws_k);
  vtrans_kernel<<<B_ * H_ * (L_ / 64), 256, 0, stream>>>(ws_qkv, ws_vt);
  flash_kernel<<<dim3(L_ / 128, B_ * H_), 256, 0, stream>>>(ws_q, ws_k, ws_vt, ws_o);
  gemm_bt<1><<<dim3(DIM_ / 128, ML_ / 128), 256, 0, stream>>>(
      ws_o, ws_w2, nullptr, out, pb, ML_, DIM_, DIM_);
}

// Round 4
// 477.849 us; speedup vs baseline: 1.0288x; 1.0109x over previous
//
#include <hip/hip_runtime.h>
#include <stdint.h>

typedef unsigned short u16;
typedef short bf16x8 __attribute__((ext_vector_type(8)));
typedef float f32x4 __attribute__((ext_vector_type(4)));

#define B_   2
#define L_   2048
#define DIM_ 2048
#define H_   16
#define D_   128
#define E3_  6144
#define ML_  4096   // B_*L_

__device__ __forceinline__ u16 f2b(float f) {
  union { float f; unsigned u; } v; v.f = f;
  return (u16)((v.u + 0x7FFFu + ((v.u >> 16) & 1u)) >> 16);
}
__device__ __forceinline__ float b2f(u16 h) {
  union { unsigned u; float f; } v; v.u = ((unsigned)h) << 16; return v.f;
}

__device__ __forceinline__ void gl_lds16(const void* g, void* l) {
  __builtin_amdgcn_global_load_lds((const __attribute__((address_space(1))) void*)g,
                                   (__attribute__((address_space(3))) void*)l, 16, 0, 0);
}

// ---------------- f32 -> bf16 convert ----------------
__global__ __launch_bounds__(256) void cvt_kernel(const float* __restrict__ in,
                                                  u16* __restrict__ out, int n4) {
  int i = blockIdx.x * 256 + threadIdx.x;
  int stride = gridDim.x * 256;
  for (; i < n4; i += stride) {
    float4 v = reinterpret_cast<const float4*>(in)[i];
    ushort4 o = make_ushort4(f2b(v.x), f2b(v.y), f2b(v.z), f2b(v.w));
    reinterpret_cast<ushort4*>(out)[i] = o;
  }
}

// ---------------- GEMM: C[M][N] = A[M][K] * Bm[N][K]^T ----------------
template<int OUTF32>
__global__ __launch_bounds__(256, 2) void gemm_bt(
    const u16* __restrict__ A, const u16* __restrict__ Bm,
    u16* __restrict__ Cb, float* __restrict__ Cf, const float* __restrict__ bias,
    int M, int N, int K) {
  __shared__ __align__(16) u16 As[128 * 32];
  __shared__ __align__(16) u16 Bs[128 * 32];
  const int tid = threadIdx.x;
  const int w = tid >> 6;
  const int g = (tid >> 4) & 3, r = tid & 15;
  const int wr = w >> 1, wc = w & 1;
  const long row0 = (long)blockIdx.y * 128, col0 = (long)blockIdx.x * 128;

  const f32x4 fz = {0.f, 0.f, 0.f, 0.f};
  f32x4 acc[4][4];
#pragma unroll
  for (int m = 0; m < 4; ++m)
#pragma unroll
    for (int n = 0; n < 4; ++n) acc[m][n] = fz;

  for (int k0 = 0; k0 < K; k0 += 32) {
#pragma unroll
    for (int it = 0; it < 2; ++it) {
      int c = it * 256 + tid;
      gl_lds16(A + (row0 + (c >> 2)) * (long)K + k0 + ((c & 3) << 3),
               (char*)As + ((it * 256 + (w << 6)) << 4));
      gl_lds16(Bm + (col0 + (c >> 2)) * (long)K + k0 + ((c & 3) << 3),
               (char*)Bs + ((it * 256 + (w << 6)) << 4));
    }
    __syncthreads();
    bf16x8 af[4], bfr[4];
#pragma unroll
    for (int m = 0; m < 4; ++m)
      af[m] = *reinterpret_cast<const bf16x8*>(As + (wr * 64 + m * 16 + r) * 32 + g * 8);
#pragma unroll
    for (int n = 0; n < 4; ++n)
      bfr[n] = *reinterpret_cast<const bf16x8*>(Bs + (wc * 64 + n * 16 + r) * 32 + g * 8);
#pragma unroll
    for (int m = 0; m < 4; ++m)
#pragma unroll
      for (int n = 0; n < 4; ++n)
        acc[m][n] = __builtin_amdgcn_mfma_f32_16x16x32_bf16(af[m], bfr[n], acc[m][n], 0, 0, 0);
    __syncthreads();
  }

#pragma unroll
  for (int m = 0; m < 4; ++m)
#pragma unroll
    for (int n = 0; n < 4; ++n)
#pragma unroll
      for (int j = 0; j < 4; ++j) {
        long rr = row0 + wr * 64 + m * 16 + g * 4 + j;
        long cc = col0 + wc * 64 + n * 16 + r;
        if constexpr (OUTF32) {
          Cf[rr * N + cc] = acc[m][n][j] + bias[cc];
        } else {
          Cb[rr * N + cc] = f2b(acc[m][n][j]);
        }
      }
}

// ---------------- RMSNorm + RoPE for q,k; scatter to [B,H,L,D] ----------------
__global__ __launch_bounds__(256) void normrope_kernel(
    const u16* __restrict__ qkv, const float* __restrict__ pe,
    const float* __restrict__ qsc, const float* __restrict__ ksc,
    u16* __restrict__ Qo, u16* __restrict__ Ko) {
  const int w = threadIdx.x >> 6, ln = threadIdx.x & 63;
  const int idx = blockIdx.x * 4 + w;          // (b*L + l)*16 + h
  const int h = idx & 15, bl = idx >> 4;
  const int l = bl & (L_ - 1), b = bl >> 11;
  const u16* base = qkv + (long)bl * E3_ + h * D_;
  const float4 pv = *reinterpret_cast<const float4*>(pe + ((long)l * 64 + ln) * 4);
  const long obase = (((long)(b * H_ + h)) * L_ + l) * D_ + 2 * ln;
  // q
  {
    unsigned qv = *reinterpret_cast<const unsigned*>(base + 2 * ln);
    float x0 = b2f((u16)qv), x1 = b2f((u16)(qv >> 16));
    float ss = x0 * x0 + x1 * x1;
#pragma unroll
    for (int msk = 1; msk < 64; msk <<= 1) ss += __shfl_xor(ss, msk);
    float rr = rsqrtf(ss * (1.0f / 128.0f) + 1e-6f);
    float y0 = x0 * rr * qsc[2 * ln], y1 = x1 * rr * qsc[2 * ln + 1];
    float o0 = pv.x * y0 + pv.y * y1, o1 = pv.z * y0 + pv.w * y1;
    *reinterpret_cast<unsigned*>(Qo + obase) = (unsigned)f2b(o0) | ((unsigned)f2b(o1) << 16);
  }
  // k
  {
    unsigned kv = *reinterpret_cast<const unsigned*>(base + DIM_ + 2 * ln);
    float x0 = b2f((u16)kv), x1 = b2f((u16)(kv >> 16));
    float ss = x0 * x0 + x1 * x1;
#pragma unroll
    for (int msk = 1; msk < 64; msk <<= 1) ss += __shfl_xor(ss, msk);
    float rr = rsqrtf(ss * (1.0f / 128.0f) + 1e-6f);
    float y0 = x0 * rr * ksc[2 * ln], y1 = x1 * rr * ksc[2 * ln + 1];
    float o0 = pv.x * y0 + pv.y * y1, o1 = pv.z * y0 + pv.w * y1;
    *reinterpret_cast<unsigned*>(Ko + obase) = (unsigned)f2b(o0) | ((unsigned)f2b(o1) << 16);
  }
}

// ---------------- V transpose: qkv v-part -> VT[B,H,D,L] ----------------
__global__ __launch_bounds__(256) void vtrans_kernel(const u16* __restrict__ qkv,
                                                     u16* __restrict__ VT) {
  __shared__ u16 t[64][132];
  const int tid = threadIdx.x;
  const int bh = blockIdx.x >> 5, lt = blockIdx.x & 31;
  const int b = bh >> 4, h = bh & 15;
  const int l0 = lt << 6;
  const u16* src = qkv + ((long)(b * L_ + l0)) * E3_ + 2 * DIM_ + h * D_;
#pragma unroll
  for (int i = 0; i < 32; ++i) {
    int o = i * 256 + tid;
    int lr = o >> 7, d = o & 127;
    t[lr][d] = src[(long)lr * E3_ + d];
  }
  __syncthreads();
  u16* dst = VT + (long)bh * (D_ * L_) + l0;
#pragma unroll
  for (int i = 0; i < 32; ++i) {
    int o = i * 256 + tid;
    int d = o >> 6, lr = o & 63;
    dst[(long)d * L_ + lr] = t[lr][d];
  }
}

// ---------------- Flash attention (8 waves x 16 q-rows, 2-phase dbuf) ----------------
__global__ __launch_bounds__(512, 2) void flash_kernel(
    const u16* __restrict__ Qg, const u16* __restrict__ Kg,
    const u16* __restrict__ Vt, u16* __restrict__ Og) {
  __shared__ __align__(16) u16 Ks[2][64 * 128];   // [kk][d]   swizzled rows of 256B
  __shared__ __align__(16) u16 Vs[2][128 * 64];   // [d][kk]   swizzled rows of 128B
  __shared__ __align__(16) u16 Ps[128 * 64];      // [q][kk]   swizzled rows of 128B
  const int tid = threadIdx.x, w = tid >> 6;
  const int g = (tid >> 4) & 3, r = tid & 15;
  const int bh = blockIdx.y, q0 = blockIdx.x * 128;
  const int b = bh >> 4, h = bh & 15;
  const u16* Qb = Qg + (long)bh * (L_ * D_);
  const u16* Kb = Kg + (long)bh * (L_ * D_);
  const u16* Vb = Vt + (long)bh * (L_ * D_);   // [128][2048]
  char* PsB = (char*)Ps;
  const float sc = 0.08838834764831845f;       // 1/sqrt(128)
  const int qrow = w * 16;                     // wave's q-row base within the 128-row tile

  bf16x8 qf[4];
#pragma unroll
  for (int t = 0; t < 4; ++t)
    qf[t] = *reinterpret_cast<const bf16x8*>(
        Qb + (long)(q0 + qrow + r) * D_ + t * 32 + g * 8);

  const f32x4 fz = {0.f, 0.f, 0.f, 0.f};
  f32x4 oacc[8];
  f32x4 mrun = (f32x4){-3.0e38f, -3.0e38f, -3.0e38f, -3.0e38f};
  f32x4 lrun = fz;
#pragma unroll
  for (int n = 0; n < 8; ++n) oacc[n] = fz;

  // stage K/V tile kt into buffer buf (512 threads: 2 passes of 16B each for K and V)
  auto stage = [&](int buf, int kt) {
    const int kk0 = kt * 64;
    const u16* Ksrc = Kb + (long)kk0 * D_;
    char* KsB = (char*)Ks[buf];
    char* VsB = (char*)Vs[buf];
#pragma unroll
    for (int it = 0; it < 2; ++it) {
      int c = it * 512 + tid;
      int pb = c << 4;
      int krow = pb >> 8;
      int klb = (pb & 255) ^ ((krow & 7) << 4);
      gl_lds16(Ksrc + (long)krow * D_ + (klb >> 1), KsB + ((it * 512 + (w << 6)) << 4));
      int vrow = pb >> 7;
      int vlb = (pb & 127) ^ ((vrow & 7) << 4);
      gl_lds16(Vb + (long)vrow * L_ + kk0 + (vlb >> 1), VsB + ((it * 512 + (w << 6)) << 4));
    }
  };

  // prologue: fill buffer 0
  stage(0, 0);
  asm volatile("s_waitcnt vmcnt(0)" ::: "memory");
  __builtin_amdgcn_s_barrier();

  for (int kt = 0; kt < 32; ++kt) {
    const int cur = kt & 1;
    if (kt + 1 < 32) stage(cur ^ 1, kt + 1);   // prefetch next tile (in flight across compute)
    const char* KsB = (const char*)Ks[cur];
    const char* VsB = (const char*)Vs[cur];

    // S = Q K^T  (per wave: 16 q rows x 64 kk)
    f32x4 s[4];
#pragma unroll
    for (int n = 0; n < 4; ++n) s[n] = fz;
    __builtin_amdgcn_s_setprio(1);
#pragma unroll
    for (int t = 0; t < 4; ++t) {
#pragma unroll
      for (int n = 0; n < 4; ++n) {
        int kr = n * 16 + r;
        bf16x8 kf = *reinterpret_cast<const bf16x8*>(
            KsB + ((kr << 8) | ((t * 64 + g * 16) ^ ((kr & 7) << 4))));
        s[n] = __builtin_amdgcn_mfma_f32_16x16x32_bf16(qf[t], kf, s[n], 0, 0, 0);
      }
    }
    __builtin_amdgcn_s_setprio(0);

    // online softmax (scaled domain), T13 defer-max
    {
      f32x4 rmx = s[0];
#pragma unroll
      for (int n = 1; n < 4; ++n)
#pragma unroll
        for (int j = 0; j < 4; ++j) rmx[j] = fmaxf(rmx[j], s[n][j]);
#pragma unroll
      for (int j = 0; j < 4; ++j) {
#pragma unroll
        for (int msk = 1; msk < 16; msk <<= 1)
          rmx[j] = fmaxf(rmx[j], __shfl_xor(rmx[j], msk));
      }
      float growth = rmx[0] * sc - mrun[0];
#pragma unroll
      for (int j = 1; j < 4; ++j) growth = fmaxf(growth, rmx[j] * sc - mrun[j]);
      if (!__all(growth <= 8.0f)) {
#pragma unroll
        for (int j = 0; j < 4; ++j) {
          float mnew = fmaxf(mrun[j], rmx[j] * sc);
          float corr = __expf(mrun[j] - mnew);
          mrun[j] = mnew;
          lrun[j] *= corr;
#pragma unroll
          for (int n = 0; n < 8; ++n) oacc[n][j] *= corr;
        }
      }
      f32x4 rsum = fz;
#pragma unroll
      for (int n = 0; n < 4; ++n) {
#pragma unroll
        for (int j = 0; j < 4; ++j) {
          float p = __expf(s[n][j] * sc - mrun[j]);
          rsum[j] += p;
          int ql = qrow + g * 4 + j;
          int col = n * 16 + r;
          *reinterpret_cast<u16*>(PsB + ((ql << 7) | ((col << 1) ^ ((ql & 7) << 4)))) = f2b(p);
        }
      }
#pragma unroll
      for (int j = 0; j < 4; ++j) {
#pragma unroll
        for (int msk = 1; msk < 16; msk <<= 1) rsum[j] += __shfl_xor(rsum[j], msk);
        lrun[j] += rsum[j];
      }
    }

    // O += P V  (A = P from LDS, B = VT from LDS)
    __builtin_amdgcn_s_setprio(1);
#pragma unroll
    for (int t = 0; t < 2; ++t) {
      int pr = qrow + r;
      bf16x8 pf = *reinterpret_cast<const bf16x8*>(
          PsB + ((pr << 7) | ((t * 64 + g * 16) ^ ((pr & 7) << 4))));
#pragma unroll
      for (int n = 0; n < 8; ++n) {
        int vr = n * 16 + r;
        bf16x8 vf = *reinterpret_cast<const bf16x8*>(
            VsB + ((vr << 7) | ((t * 64 + g * 16) ^ ((vr & 7) << 4))));
        oacc[n] = __builtin_amdgcn_mfma_f32_16x16x32_bf16(pf, vf, oacc[n], 0, 0, 0);
      }
    }
    __builtin_amdgcn_s_setprio(0);

    // end of iter: next tile's loads complete; all waves done with buf[cur]
    asm volatile("s_waitcnt vmcnt(0)" ::: "memory");
    __builtin_amdgcn_s_barrier();
  }

  // epilogue: O /= l, write [B, L, H*D]
  {
    f32x4 inv;
#pragma unroll
    for (int j = 0; j < 4; ++j) inv[j] = 1.0f / lrun[j];
#pragma unroll
    for (int n = 0; n < 8; ++n)
#pragma unroll
      for (int j = 0; j < 4; ++j) {
        int ql = qrow + g * 4 + j;
        int col = n * 16 + r;
        Og[((long)(b * L_) + q0 + ql) * DIM_ + h * D_ + col] = f2b(oacc[n][j] * inv[j]);
      }
  }
}

extern "C" void kernel_launch(void* const* d_in, const int* in_sizes, int n_in,
                              void* d_out, int out_size, void* d_ws, size_t ws_size,
                              hipStream_t stream) {
  const float* x    = (const float*)d_in[0];
  const float* pe   = (const float*)d_in[1];
  const float* qkvw = (const float*)d_in[2];
  const float* qsc  = (const float*)d_in[3];
  const float* ksc  = (const float*)d_in[4];
  const float* pw   = (const float*)d_in[5];
  const float* pb   = (const float*)d_in[6];
  float* out = (float*)d_out;

  u16* ws_x   = (u16*)d_ws;                   //  8,388,608 elems
  u16* ws_w1  = ws_x   + (size_t)ML_ * DIM_;  // 12,582,912
  u16* ws_w2  = ws_w1  + (size_t)E3_ * DIM_;  //  4,194,304
  u16* ws_qkv = ws_w2  + (size_t)DIM_ * DIM_; // 25,165,824
  u16* ws_q   = ws_qkv + (size_t)ML_ * E3_;   //  8,388,608
  u16* ws_k   = ws_q   + (size_t)ML_ * DIM_;
  u16* ws_vt  = ws_k   + (size_t)ML_ * DIM_;
  u16* ws_o   = ws_vt  + (size_t)ML_ * DIM_;  // total 160 MiB

  cvt_kernel<<<2048, 256, 0, stream>>>(x, ws_x, ML_ * DIM_ / 4);
  cvt_kernel<<<2048, 256, 0, stream>>>(qkvw, ws_w1, E3_ * DIM_ / 4);
  cvt_kernel<<<2048, 256, 0, stream>>>(pw, ws_w2, DIM_ * DIM_ / 4);

  gemm_bt<0><<<dim3(E3_ / 128, ML_ / 128), 256, 0, stream>>>(
      ws_x, ws_w1, ws_qkv, nullptr, nullptr, ML_, E3_, DIM_);
  normrope_kernel<<<(B_ * L_ * H_) / 4, 256, 0, stream>>>(ws_qkv, pe, qsc, ksc, ws_q, ws_k);
  vtrans_kernel<<<B_ * H_ * (L_ / 64), 256, 0, stream>>>(ws_qkv, ws_vt);
  flash_kernel<<<dim3(L_ / 128, B_ * H_), 512, 0, stream>>>(ws_q, ws_k, ws_vt, ws_o);
  gemm_bt<1><<<dim3(DIM_ / 128, ML_ / 128), 256, 0, stream>>>(
      ws_o, ws_w2, nullptr, out, pb, ML_, DIM_, DIM_);
}

// Round 5
// 430.855 us; speedup vs baseline: 1.1410x; 1.1091x over previous
//
#include <hip/hip_runtime.h>
#include <stdint.h>

typedef unsigned short u16;
typedef short bf16x8 __attribute__((ext_vector_type(8)));
typedef float f32x4 __attribute__((ext_vector_type(4)));

#define B_   2
#define L_   2048
#define DIM_ 2048
#define H_   16
#define D_   128
#define E3_  6144
#define ML_  4096   // B_*L_

__device__ __forceinline__ u16 f2b(float f) {
  union { float f; unsigned u; } v; v.f = f;
  return (u16)((v.u + 0x7FFFu + ((v.u >> 16) & 1u)) >> 16);
}
__device__ __forceinline__ float b2f(u16 h) {
  union { unsigned u; float f; } v; v.u = ((unsigned)h) << 16; return v.f;
}

__device__ __forceinline__ void gl_lds16(const void* g, void* l) {
  __builtin_amdgcn_global_load_lds((const __attribute__((address_space(1))) void*)g,
                                   (__attribute__((address_space(3))) void*)l, 16, 0, 0);
}

// ---------------- f32 -> bf16 convert ----------------
__global__ __launch_bounds__(256) void cvt_kernel(const float* __restrict__ in,
                                                  u16* __restrict__ out, int n4) {
  int i = blockIdx.x * 256 + threadIdx.x;
  int stride = gridDim.x * 256;
  for (; i < n4; i += stride) {
    float4 v = reinterpret_cast<const float4*>(in)[i];
    ushort4 o = make_ushort4(f2b(v.x), f2b(v.y), f2b(v.z), f2b(v.w));
    reinterpret_cast<ushort4*>(out)[i] = o;
  }
}

// ---------------- GEMM: C[M][N] = A[M][K] * Bm[N][K]^T ----------------
template<int OUTF32>
__global__ __launch_bounds__(256, 3) void gemm_bt(
    const u16* __restrict__ A, const u16* __restrict__ Bm,
    u16* __restrict__ Cb, float* __restrict__ Cf, const float* __restrict__ bias,
    int M, int N, int K) {
  __shared__ __align__(16) u16 As[128 * 32];
  __shared__ __align__(16) u16 Bs[128 * 32];
  const int tid = threadIdx.x;
  const int w = tid >> 6;
  const int g = (tid >> 4) & 3, r = tid & 15;
  const int wr = w >> 1, wc = w & 1;
  const long row0 = (long)blockIdx.y * 128, col0 = (long)blockIdx.x * 128;

  const f32x4 fz = {0.f, 0.f, 0.f, 0.f};
  f32x4 acc[4][4];
#pragma unroll
  for (int m = 0; m < 4; ++m)
#pragma unroll
    for (int n = 0; n < 4; ++n) acc[m][n] = fz;

  for (int k0 = 0; k0 < K; k0 += 32) {
#pragma unroll
    for (int it = 0; it < 2; ++it) {
      int c = it * 256 + tid;
      gl_lds16(A + (row0 + (c >> 2)) * (long)K + k0 + ((c & 3) << 3),
               (char*)As + ((it * 256 + (w << 6)) << 4));
      gl_lds16(Bm + (col0 + (c >> 2)) * (long)K + k0 + ((c & 3) << 3),
               (char*)Bs + ((it * 256 + (w << 6)) << 4));
    }
    __syncthreads();
    bf16x8 af[4], bfr[4];
#pragma unroll
    for (int m = 0; m < 4; ++m)
      af[m] = *reinterpret_cast<const bf16x8*>(As + (wr * 64 + m * 16 + r) * 32 + g * 8);
#pragma unroll
    for (int n = 0; n < 4; ++n)
      bfr[n] = *reinterpret_cast<const bf16x8*>(Bs + (wc * 64 + n * 16 + r) * 32 + g * 8);
#pragma unroll
    for (int m = 0; m < 4; ++m)
#pragma unroll
      for (int n = 0; n < 4; ++n)
        acc[m][n] = __builtin_amdgcn_mfma_f32_16x16x32_bf16(af[m], bfr[n], acc[m][n], 0, 0, 0);
    __syncthreads();
  }

#pragma unroll
  for (int m = 0; m < 4; ++m)
#pragma unroll
    for (int n = 0; n < 4; ++n)
#pragma unroll
      for (int j = 0; j < 4; ++j) {
        long rr = row0 + wr * 64 + m * 16 + g * 4 + j;
        long cc = col0 + wc * 64 + n * 16 + r;
        if constexpr (OUTF32) {
          Cf[rr * N + cc] = acc[m][n][j] + bias[cc];
        } else {
          Cb[rr * N + cc] = f2b(acc[m][n][j]);
        }
      }
}

// ---------------- RMSNorm + RoPE for q,k; scatter to [B,H,L,D] ----------------
__global__ __launch_bounds__(256) void normrope_kernel(
    const u16* __restrict__ qkv, const float* __restrict__ pe,
    const float* __restrict__ qsc, const float* __restrict__ ksc,
    u16* __restrict__ Qo, u16* __restrict__ Ko) {
  const int w = threadIdx.x >> 6, ln = threadIdx.x & 63;
  const int idx = blockIdx.x * 4 + w;          // (b*L + l)*16 + h
  const int h = idx & 15, bl = idx >> 4;
  const int l = bl & (L_ - 1), b = bl >> 11;
  const u16* base = qkv + (long)bl * E3_ + h * D_;
  const float4 pv = *reinterpret_cast<const float4*>(pe + ((long)l * 64 + ln) * 4);
  const long obase = (((long)(b * H_ + h)) * L_ + l) * D_ + 2 * ln;
  // q
  {
    unsigned qv = *reinterpret_cast<const unsigned*>(base + 2 * ln);
    float x0 = b2f((u16)qv), x1 = b2f((u16)(qv >> 16));
    float ss = x0 * x0 + x1 * x1;
#pragma unroll
    for (int msk = 1; msk < 64; msk <<= 1) ss += __shfl_xor(ss, msk);
    float rr = rsqrtf(ss * (1.0f / 128.0f) + 1e-6f);
    float y0 = x0 * rr * qsc[2 * ln], y1 = x1 * rr * qsc[2 * ln + 1];
    float o0 = pv.x * y0 + pv.y * y1, o1 = pv.z * y0 + pv.w * y1;
    *reinterpret_cast<unsigned*>(Qo + obase) = (unsigned)f2b(o0) | ((unsigned)f2b(o1) << 16);
  }
  // k
  {
    unsigned kv = *reinterpret_cast<const unsigned*>(base + DIM_ + 2 * ln);
    float x0 = b2f((u16)kv), x1 = b2f((u16)(kv >> 16));
    float ss = x0 * x0 + x1 * x1;
#pragma unroll
    for (int msk = 1; msk < 64; msk <<= 1) ss += __shfl_xor(ss, msk);
    float rr = rsqrtf(ss * (1.0f / 128.0f) + 1e-6f);
    float y0 = x0 * rr * ksc[2 * ln], y1 = x1 * rr * ksc[2 * ln + 1];
    float o0 = pv.x * y0 + pv.y * y1, o1 = pv.z * y0 + pv.w * y1;
    *reinterpret_cast<unsigned*>(Ko + obase) = (unsigned)f2b(o0) | ((unsigned)f2b(o1) << 16);
  }
}

// ---------------- V transpose: qkv v-part -> VT[B,H,D,L] ----------------
__global__ __launch_bounds__(256) void vtrans_kernel(const u16* __restrict__ qkv,
                                                     u16* __restrict__ VT) {
  __shared__ u16 t[64][132];
  const int tid = threadIdx.x;
  const int bh = blockIdx.x >> 5, lt = blockIdx.x & 31;
  const int b = bh >> 4, h = bh & 15;
  const int l0 = lt << 6;
  const u16* src = qkv + ((long)(b * L_ + l0)) * E3_ + 2 * DIM_ + h * D_;
#pragma unroll
  for (int i = 0; i < 32; ++i) {
    int o = i * 256 + tid;
    int lr = o >> 7, d = o & 127;
    t[lr][d] = src[(long)lr * E3_ + d];
  }
  __syncthreads();
  u16* dst = VT + (long)bh * (D_ * L_) + l0;
#pragma unroll
  for (int i = 0; i < 32; ++i) {
    int o = i * 256 + tid;
    int d = o >> 6, lr = o & 63;
    dst[(long)d * L_ + lr] = t[lr][d];
  }
}

// ---------------- Flash attention (8 waves x 16 q-rows, fixed-max softmax) ----------------
__global__ __launch_bounds__(512, 2) void flash_kernel(
    const u16* __restrict__ Qg, const u16* __restrict__ Kg,
    const u16* __restrict__ Vt, u16* __restrict__ Og) {
  __shared__ __align__(16) u16 Ks[2][64 * 128];   // [kk][d]   swizzled rows of 256B
  __shared__ __align__(16) u16 Vs[2][128 * 64];   // [d][kk]   swizzled rows of 128B
  __shared__ __align__(16) u16 Ps[128 * 64];      // [q][kk]   swizzled rows of 128B
  const int tid = threadIdx.x, w = tid >> 6;
  const int g = (tid >> 4) & 3, r = tid & 15;
  const int bh = blockIdx.y, q0 = blockIdx.x * 128;
  const int b = bh >> 4, h = bh & 15;
  const u16* Qb = Qg + (long)bh * (L_ * D_);
  const u16* Kb = Kg + (long)bh * (L_ * D_);
  const u16* Vb = Vt + (long)bh * (L_ * D_);   // [128][2048]
  char* PsB = (char*)Ps;
  const float sc = 0.08838834764831845f;       // 1/sqrt(128)
  const int qrow = w * 16;                     // wave's q-row base within the 128-row tile

  bf16x8 qf[4];
#pragma unroll
  for (int t = 0; t < 4; ++t)
    qf[t] = *reinterpret_cast<const bf16x8*>(
        Qb + (long)(q0 + qrow + r) * D_ + t * 32 + g * 8);

  bf16x8 vone;
#pragma unroll
  for (int j = 0; j < 8; ++j) vone[j] = (short)0x3F80;   // bf16 1.0

  const f32x4 fz = {0.f, 0.f, 0.f, 0.f};
  f32x4 oacc[8];
  f32x4 lacc = fz;                             // row sums of P (via MFMA-ones)
#pragma unroll
  for (int n = 0; n < 8; ++n) oacc[n] = fz;

  // stage K/V tile kt into buffer buf (512 threads: 2 passes of 16B each for K and V)
  auto stage = [&](int buf, int kt) {
    const int kk0 = kt * 64;
    const u16* Ksrc = Kb + (long)kk0 * D_;
    char* KsB = (char*)Ks[buf];
    char* VsB = (char*)Vs[buf];
#pragma unroll
    for (int it = 0; it < 2; ++it) {
      int c = it * 512 + tid;
      int pb = c << 4;
      int krow = pb >> 8;
      int klb = (pb & 255) ^ ((krow & 7) << 4);
      gl_lds16(Ksrc + (long)krow * D_ + (klb >> 1), KsB + ((it * 512 + (w << 6)) << 4));
      int vrow = pb >> 7;
      int vlb = (pb & 127) ^ ((vrow & 7) << 4);
      gl_lds16(Vb + (long)vrow * L_ + kk0 + (vlb >> 1), VsB + ((it * 512 + (w << 6)) << 4));
    }
  };

  // prologue: fill buffer 0
  stage(0, 0);
  asm volatile("s_waitcnt vmcnt(0)" ::: "memory");
  __builtin_amdgcn_s_barrier();

  for (int kt = 0; kt < 32; ++kt) {
    const int cur = kt & 1;
    if (kt + 1 < 32) stage(cur ^ 1, kt + 1);   // prefetch next tile (in flight across compute)
    const char* KsB = (const char*)Ks[cur];
    const char* VsB = (const char*)Vs[cur];

    // S = Q K^T  (per wave: 16 q rows x 64 kk)
    f32x4 s[4];
#pragma unroll
    for (int n = 0; n < 4; ++n) s[n] = fz;
    __builtin_amdgcn_s_setprio(1);
#pragma unroll
    for (int t = 0; t < 4; ++t) {
#pragma unroll
      for (int n = 0; n < 4; ++n) {
        int kr = n * 16 + r;
        bf16x8 kf = *reinterpret_cast<const bf16x8*>(
            KsB + ((kr << 8) | ((t * 64 + g * 16) ^ ((kr & 7) << 4))));
        s[n] = __builtin_amdgcn_mfma_f32_16x16x32_bf16(qf[t], kf, s[n], 0, 0, 0);
      }
    }
    __builtin_amdgcn_s_setprio(0);

    // fixed-max softmax: p = exp(S*sc - 20); row sums come from MFMA-ones in PV
#pragma unroll
    for (int n = 0; n < 4; ++n) {
#pragma unroll
      for (int j = 0; j < 4; ++j) {
        float p = __expf(s[n][j] * sc - 20.0f);
        int ql = qrow + g * 4 + j;
        int col = n * 16 + r;
        *reinterpret_cast<u16*>(PsB + ((ql << 7) | ((col << 1) ^ ((ql & 7) << 4)))) = f2b(p);
      }
    }

    // O += P V  (A = P from LDS, B = VT from LDS); lacc += P * ones (row sums)
    __builtin_amdgcn_s_setprio(1);
#pragma unroll
    for (int t = 0; t < 2; ++t) {
      int pr = qrow + r;
      bf16x8 pf = *reinterpret_cast<const bf16x8*>(
          PsB + ((pr << 7) | ((t * 64 + g * 16) ^ ((pr & 7) << 4))));
      lacc = __builtin_amdgcn_mfma_f32_16x16x32_bf16(pf, vone, lacc, 0, 0, 0);
#pragma unroll
      for (int n = 0; n < 8; ++n) {
        int vr = n * 16 + r;
        bf16x8 vf = *reinterpret_cast<const bf16x8*>(
            VsB + ((vr << 7) | ((t * 64 + g * 16) ^ ((vr & 7) << 4))));
        oacc[n] = __builtin_amdgcn_mfma_f32_16x16x32_bf16(pf, vf, oacc[n], 0, 0, 0);
      }
    }
    __builtin_amdgcn_s_setprio(0);

    // end of iter: next tile's loads complete; all waves done with buf[cur]
    asm volatile("s_waitcnt vmcnt(0)" ::: "memory");
    __builtin_amdgcn_s_barrier();
  }

  // epilogue: O /= l, write [B, L, H*D]
  {
    f32x4 inv;
#pragma unroll
    for (int j = 0; j < 4; ++j) inv[j] = 1.0f / lacc[j];
#pragma unroll
    for (int n = 0; n < 8; ++n)
#pragma unroll
      for (int j = 0; j < 4; ++j) {
        int ql = qrow + g * 4 + j;
        int col = n * 16 + r;
        Og[((long)(b * L_) + q0 + ql) * DIM_ + h * D_ + col] = f2b(oacc[n][j] * inv[j]);
      }
  }
}

extern "C" void kernel_launch(void* const* d_in, const int* in_sizes, int n_in,
                              void* d_out, int out_size, void* d_ws, size_t ws_size,
                              hipStream_t stream) {
  const float* x    = (const float*)d_in[0];
  const float* pe   = (const float*)d_in[1];
  const float* qkvw = (const float*)d_in[2];
  const float* qsc  = (const float*)d_in[3];
  const float* ksc  = (const float*)d_in[4];
  const float* pw   = (const float*)d_in[5];
  const float* pb   = (const float*)d_in[6];
  float* out = (float*)d_out;

  u16* ws_x   = (u16*)d_ws;                   //  8,388,608 elems
  u16* ws_w1  = ws_x   + (size_t)ML_ * DIM_;  // 12,582,912
  u16* ws_w2  = ws_w1  + (size_t)E3_ * DIM_;  //  4,194,304
  u16* ws_qkv = ws_w2  + (size_t)DIM_ * DIM_; // 25,165,824
  u16* ws_q   = ws_qkv + (size_t)ML_ * E3_;   //  8,388,608
  u16* ws_k   = ws_q   + (size_t)ML_ * DIM_;
  u16* ws_vt  = ws_k   + (size_t)ML_ * DIM_;
  u16* ws_o   = ws_vt  + (size_t)ML_ * DIM_;  // total 160 MiB

  cvt_kernel<<<2048, 256, 0, stream>>>(x, ws_x, ML_ * DIM_ / 4);
  cvt_kernel<<<2048, 256, 0, stream>>>(qkvw, ws_w1, E3_ * DIM_ / 4);
  cvt_kernel<<<2048, 256, 0, stream>>>(pw, ws_w2, DIM_ * DIM_ / 4);

  gemm_bt<0><<<dim3(E3_ / 128, ML_ / 128), 256, 0, stream>>>(
      ws_x, ws_w1, ws_qkv, nullptr, nullptr, ML_, E3_, DIM_);
  normrope_kernel<<<(B_ * L_ * H_) / 4, 256, 0, stream>>>(ws_qkv, pe, qsc, ksc, ws_q, ws_k);
  vtrans_kernel<<<B_ * H_ * (L_ / 64), 256, 0, stream>>>(ws_qkv, ws_vt);
  flash_kernel<<<dim3(L_ / 128, B_ * H_), 512, 0, stream>>>(ws_q, ws_k, ws_vt, ws_o);
  gemm_bt<1><<<dim3(DIM_ / 128, ML_ / 128), 256, 0, stream>>>(
      ws_o, ws_w2, nullptr, out, pb, ML_, DIM_, DIM_);
}

// Round 6
// 426.751 us; speedup vs baseline: 1.1520x; 1.0096x over previous
//
#include <hip/hip_runtime.h>
#include <stdint.h>

typedef unsigned short u16;
typedef short bf16x8 __attribute__((ext_vector_type(8)));
typedef float f32x4 __attribute__((ext_vector_type(4)));

#define B_   2
#define L_   2048
#define DIM_ 2048
#define H_   16
#define D_   128
#define E3_  6144
#define ML_  4096   // B_*L_

__device__ __forceinline__ u16 f2b(float f) {
  union { float f; unsigned u; } v; v.f = f;
  return (u16)((v.u + 0x7FFFu + ((v.u >> 16) & 1u)) >> 16);
}
__device__ __forceinline__ float b2f(u16 h) {
  union { unsigned u; float f; } v; v.u = ((unsigned)h) << 16; return v.f;
}

__device__ __forceinline__ void gl_lds16(const void* g, void* l) {
  __builtin_amdgcn_global_load_lds((const __attribute__((address_space(1))) void*)g,
                                   (__attribute__((address_space(3))) void*)l, 16, 0, 0);
}

// ---------------- f32 -> bf16 convert ----------------
__global__ __launch_bounds__(256) void cvt_kernel(const float* __restrict__ in,
                                                  u16* __restrict__ out, int n4) {
  int i = blockIdx.x * 256 + threadIdx.x;
  int stride = gridDim.x * 256;
  for (; i < n4; i += stride) {
    float4 v = reinterpret_cast<const float4*>(in)[i];
    ushort4 o = make_ushort4(f2b(v.x), f2b(v.y), f2b(v.z), f2b(v.w));
    reinterpret_cast<ushort4*>(out)[i] = o;
  }
}

// ---------------- 256x256 8-phase GEMM (bf16 out): C[M][N] = A[M][K] * Bm[N][K]^T ----------------
__global__ __launch_bounds__(512, 1) void gemm256_bt(
    const u16* __restrict__ A, const u16* __restrict__ Bm,
    u16* __restrict__ Cb, int M, int N, int K) {
  // [dbuf][mat A/B][half][128 rows][64 cols] bf16, rows 128B, XOR-swizzled ((row&7)<<4)
  __shared__ __align__(16) u16 lds[2][2][2][128 * 64];
  const int tid = threadIdx.x, w = tid >> 6;
  const int g = (tid >> 4) & 3, r = tid & 15;
  const int wm = w >> 2, wn = w & 3;
  const long row0 = (long)blockIdx.y * 256, col0 = (long)blockIdx.x * 256;
  const int sw = (r & 7) << 4;   // read-side swizzle (row&7 == r&7 for all our rows)

  const f32x4 fz = {0.f, 0.f, 0.f, 0.f};
  f32x4 acc[8][4];
#pragma unroll
  for (int m = 0; m < 8; ++m)
#pragma unroll
    for (int n = 0; n < 4; ++n) acc[m][n] = fz;

  // burst-stage K-tile kt into dbuf bb: 8 x gl_lds16 per thread (4 half-tiles)
  auto stage = [&](int bb, int kt) {
    const long k0 = (long)kt * 64;
#pragma unroll
    for (int ld = 0; ld < 8; ++ld) {
      const int mat = ld >> 2, half = (ld >> 1) & 1, it = ld & 1;
      int c = it * 512 + tid;              // [0,1024): 128 rows x 8 x 16B
      int rowl = c >> 3;
      int scb = ((c & 7) << 4) ^ ((rowl & 7) << 4);   // pre-swizzled source col byte
      const u16* src = (mat == 0 ? A + (row0 + half * 128 + rowl) * (long)K
                                 : Bm + (col0 + half * 128 + rowl) * (long)K)
                       + k0 + (scb >> 1);
      gl_lds16(src, (char*)lds[bb][mat][half] + ((it * 512 + (w << 6)) << 4));
    }
  };

  const int NT = K >> 6;
  stage(0, 0);
  asm volatile("s_waitcnt vmcnt(0)" ::: "memory");
  __builtin_amdgcn_s_barrier();

  for (int kt = 0; kt < NT; ++kt) {
    const int bb = kt & 1;
    const char* Ah = (const char*)lds[bb][0][wm];        // this wave's A half
    const char* Bh = (const char*)lds[bb][1][wn >> 1];   // this wave's B half
    const int brow0 = (wn & 1) * 64;

    if (kt + 1 < NT) stage(bb ^ 1, kt + 1);   // burst prefetch, in flight across phases

    // B fragments once per K-tile (reused by all 4 phases)
    bf16x8 bfr[4][2];
#pragma unroll
    for (int n = 0; n < 4; ++n)
#pragma unroll
      for (int kk = 0; kk < 2; ++kk) {
        int row = brow0 + n * 16 + r;
        bfr[n][kk] = *reinterpret_cast<const bf16x8*>(
            Bh + row * 128 + ((kk * 64 + g * 16) ^ sw));
      }

#pragma unroll
    for (int p = 0; p < 4; ++p) {
      bf16x8 af[2][2];
#pragma unroll
      for (int mm = 0; mm < 2; ++mm)
#pragma unroll
        for (int kk = 0; kk < 2; ++kk) {
          int row = (2 * p + mm) * 16 + r;
          af[mm][kk] = *reinterpret_cast<const bf16x8*>(
              Ah + row * 128 + ((kk * 64 + g * 16) ^ sw));
        }
      __builtin_amdgcn_s_barrier();
      __builtin_amdgcn_s_setprio(1);
#pragma unroll
      for (int kk = 0; kk < 2; ++kk)
#pragma unroll
        for (int n = 0; n < 4; ++n)
#pragma unroll
          for (int mm = 0; mm < 2; ++mm)
            acc[2 * p + mm][n] = __builtin_amdgcn_mfma_f32_16x16x32_bf16(
                af[mm][kk], bfr[n][kk], acc[2 * p + mm][n], 0, 0, 0);
      __builtin_amdgcn_s_setprio(0);
      if (p == 3) asm volatile("s_waitcnt vmcnt(0)" ::: "memory");  // K-tile boundary drain (covered ~3 phases)
      __builtin_amdgcn_s_barrier();
    }
  }

  // epilogue: bf16 C write
#pragma unroll
  for (int m = 0; m < 8; ++m)
#pragma unroll
    for (int n = 0; n < 4; ++n)
#pragma unroll
      for (int j = 0; j < 4; ++j) {
        long rr = row0 + wm * 128 + m * 16 + g * 4 + j;
        long cc = col0 + wn * 64 + n * 16 + r;
        Cb[rr * (long)N + cc] = f2b(acc[m][n][j]);
      }
}

// ---------------- GEMM 128^2 (f32 out + bias): C[M][N] = A[M][K] * Bm[N][K]^T ----------------
template<int OUTF32>
__global__ __launch_bounds__(256, 3) void gemm_bt(
    const u16* __restrict__ A, const u16* __restrict__ Bm,
    u16* __restrict__ Cb, float* __restrict__ Cf, const float* __restrict__ bias,
    int M, int N, int K) {
  __shared__ __align__(16) u16 As[128 * 32];
  __shared__ __align__(16) u16 Bs[128 * 32];
  const int tid = threadIdx.x;
  const int w = tid >> 6;
  const int g = (tid >> 4) & 3, r = tid & 15;
  const int wr = w >> 1, wc = w & 1;
  const long row0 = (long)blockIdx.y * 128, col0 = (long)blockIdx.x * 128;

  const f32x4 fz = {0.f, 0.f, 0.f, 0.f};
  f32x4 acc[4][4];
#pragma unroll
  for (int m = 0; m < 4; ++m)
#pragma unroll
    for (int n = 0; n < 4; ++n) acc[m][n] = fz;

  for (int k0 = 0; k0 < K; k0 += 32) {
#pragma unroll
    for (int it = 0; it < 2; ++it) {
      int c = it * 256 + tid;
      gl_lds16(A + (row0 + (c >> 2)) * (long)K + k0 + ((c & 3) << 3),
               (char*)As + ((it * 256 + (w << 6)) << 4));
      gl_lds16(Bm + (col0 + (c >> 2)) * (long)K + k0 + ((c & 3) << 3),
               (char*)Bs + ((it * 256 + (w << 6)) << 4));
    }
    __syncthreads();
    bf16x8 af[4], bfr[4];
#pragma unroll
    for (int m = 0; m < 4; ++m)
      af[m] = *reinterpret_cast<const bf16x8*>(As + (wr * 64 + m * 16 + r) * 32 + g * 8);
#pragma unroll
    for (int n = 0; n < 4; ++n)
      bfr[n] = *reinterpret_cast<const bf16x8*>(Bs + (wc * 64 + n * 16 + r) * 32 + g * 8);
#pragma unroll
    for (int m = 0; m < 4; ++m)
#pragma unroll
      for (int n = 0; n < 4; ++n)
        acc[m][n] = __builtin_amdgcn_mfma_f32_16x16x32_bf16(af[m], bfr[n], acc[m][n], 0, 0, 0);
    __syncthreads();
  }

#pragma unroll
  for (int m = 0; m < 4; ++m)
#pragma unroll
    for (int n = 0; n < 4; ++n)
#pragma unroll
      for (int j = 0; j < 4; ++j) {
        long rr = row0 + wr * 64 + m * 16 + g * 4 + j;
        long cc = col0 + wc * 64 + n * 16 + r;
        if constexpr (OUTF32) {
          Cf[rr * N + cc] = acc[m][n][j] + bias[cc];
        } else {
          Cb[rr * N + cc] = f2b(acc[m][n][j]);
        }
      }
}

// ---------------- RMSNorm + RoPE for q,k; scatter to [B,H,L,D] ----------------
__global__ __launch_bounds__(256) void normrope_kernel(
    const u16* __restrict__ qkv, const float* __restrict__ pe,
    const float* __restrict__ qsc, const float* __restrict__ ksc,
    u16* __restrict__ Qo, u16* __restrict__ Ko) {
  const int w = threadIdx.x >> 6, ln = threadIdx.x & 63;
  const int idx = blockIdx.x * 4 + w;          // (b*L + l)*16 + h
  const int h = idx & 15, bl = idx >> 4;
  const int l = bl & (L_ - 1), b = bl >> 11;
  const u16* base = qkv + (long)bl * E3_ + h * D_;
  const float4 pv = *reinterpret_cast<const float4*>(pe + ((long)l * 64 + ln) * 4);
  const long obase = (((long)(b * H_ + h)) * L_ + l) * D_ + 2 * ln;
  // q
  {
    unsigned qv = *reinterpret_cast<const unsigned*>(base + 2 * ln);
    float x0 = b2f((u16)qv), x1 = b2f((u16)(qv >> 16));
    float ss = x0 * x0 + x1 * x1;
#pragma unroll
    for (int msk = 1; msk < 64; msk <<= 1) ss += __shfl_xor(ss, msk);
    float rr = rsqrtf(ss * (1.0f / 128.0f) + 1e-6f);
    float y0 = x0 * rr * qsc[2 * ln], y1 = x1 * rr * qsc[2 * ln + 1];
    float o0 = pv.x * y0 + pv.y * y1, o1 = pv.z * y0 + pv.w * y1;
    *reinterpret_cast<unsigned*>(Qo + obase) = (unsigned)f2b(o0) | ((unsigned)f2b(o1) << 16);
  }
  // k
  {
    unsigned kv = *reinterpret_cast<const unsigned*>(base + DIM_ + 2 * ln);
    float x0 = b2f((u16)kv), x1 = b2f((u16)(kv >> 16));
    float ss = x0 * x0 + x1 * x1;
#pragma unroll
    for (int msk = 1; msk < 64; msk <<= 1) ss += __shfl_xor(ss, msk);
    float rr = rsqrtf(ss * (1.0f / 128.0f) + 1e-6f);
    float y0 = x0 * rr * ksc[2 * ln], y1 = x1 * rr * ksc[2 * ln + 1];
    float o0 = pv.x * y0 + pv.y * y1, o1 = pv.z * y0 + pv.w * y1;
    *reinterpret_cast<unsigned*>(Ko + obase) = (unsigned)f2b(o0) | ((unsigned)f2b(o1) << 16);
  }
}

// ---------------- V transpose: qkv v-part -> VT[B,H,D,L] ----------------
__global__ __launch_bounds__(256) void vtrans_kernel(const u16* __restrict__ qkv,
                                                     u16* __restrict__ VT) {
  __shared__ u16 t[64][132];
  const int tid = threadIdx.x;
  const int bh = blockIdx.x >> 5, lt = blockIdx.x & 31;
  const int b = bh >> 4, h = bh & 15;
  const int l0 = lt << 6;
  const u16* src = qkv + ((long)(b * L_ + l0)) * E3_ + 2 * DIM_ + h * D_;
#pragma unroll
  for (int i = 0; i < 32; ++i) {
    int o = i * 256 + tid;
    int lr = o >> 7, d = o & 127;
    t[lr][d] = src[(long)lr * E3_ + d];
  }
  __syncthreads();
  u16* dst = VT + (long)bh * (D_ * L_) + l0;
#pragma unroll
  for (int i = 0; i < 32; ++i) {
    int o = i * 256 + tid;
    int d = o >> 6, lr = o & 63;
    dst[(long)d * L_ + lr] = t[lr][d];
  }
}

// ---------------- Flash attention (8 waves x 16 q-rows, fixed-max softmax) ----------------
__global__ __launch_bounds__(512, 2) void flash_kernel(
    const u16* __restrict__ Qg, const u16* __restrict__ Kg,
    const u16* __restrict__ Vt, u16* __restrict__ Og) {
  __shared__ __align__(16) u16 Ks[2][64 * 128];   // [kk][d]   swizzled rows of 256B
  __shared__ __align__(16) u16 Vs[2][128 * 64];   // [d][kk]   swizzled rows of 128B
  __shared__ __align__(16) u16 Ps[128 * 64];      // [q][kk]   swizzled rows of 128B
  const int tid = threadIdx.x, w = tid >> 6;
  const int g = (tid >> 4) & 3, r = tid & 15;
  const int bh = blockIdx.y, q0 = blockIdx.x * 128;
  const int b = bh >> 4, h = bh & 15;
  const u16* Qb = Qg + (long)bh * (L_ * D_);
  const u16* Kb = Kg + (long)bh * (L_ * D_);
  const u16* Vb = Vt + (long)bh * (L_ * D_);   // [128][2048]
  char* PsB = (char*)Ps;
  const float sc = 0.08838834764831845f;       // 1/sqrt(128)
  const int qrow = w * 16;                     // wave's q-row base within the 128-row tile

  bf16x8 qf[4];
#pragma unroll
  for (int t = 0; t < 4; ++t)
    qf[t] = *reinterpret_cast<const bf16x8*>(
        Qb + (long)(q0 + qrow + r) * D_ + t * 32 + g * 8);

  bf16x8 vone;
#pragma unroll
  for (int j = 0; j < 8; ++j) vone[j] = (short)0x3F80;   // bf16 1.0

  const f32x4 fz = {0.f, 0.f, 0.f, 0.f};
  f32x4 oacc[8];
  f32x4 lacc = fz;                             // row sums of P (via MFMA-ones)
#pragma unroll
  for (int n = 0; n < 8; ++n) oacc[n] = fz;

  // stage K/V tile kt into buffer buf (512 threads: 2 passes of 16B each for K and V)
  auto stage = [&](int buf, int kt) {
    const int kk0 = kt * 64;
    const u16* Ksrc = Kb + (long)kk0 * D_;
    char* KsB = (char*)Ks[buf];
    char* VsB = (char*)Vs[buf];
#pragma unroll
    for (int it = 0; it < 2; ++it) {
      int c = it * 512 + tid;
      int pb = c << 4;
      int krow = pb >> 8;
      int klb = (pb & 255) ^ ((krow & 7) << 4);
      gl_lds16(Ksrc + (long)krow * D_ + (klb >> 1), KsB + ((it * 512 + (w << 6)) << 4));
      int vrow = pb >> 7;
      int vlb = (pb & 127) ^ ((vrow & 7) << 4);
      gl_lds16(Vb + (long)vrow * L_ + kk0 + (vlb >> 1), VsB + ((it * 512 + (w << 6)) << 4));
    }
  };

  // prologue: fill buffer 0
  stage(0, 0);
  asm volatile("s_waitcnt vmcnt(0)" ::: "memory");
  __builtin_amdgcn_s_barrier();

  for (int kt = 0; kt < 32; ++kt) {
    const int cur = kt & 1;
    if (kt + 1 < 32) stage(cur ^ 1, kt + 1);   // prefetch next tile (in flight across compute)
    const char* KsB = (const char*)Ks[cur];
    const char* VsB = (const char*)Vs[cur];

    // S = Q K^T  (per wave: 16 q rows x 64 kk)
    f32x4 s[4];
#pragma unroll
    for (int n = 0; n < 4; ++n) s[n] = fz;
    __builtin_amdgcn_s_setprio(1);
#pragma unroll
    for (int t = 0; t < 4; ++t) {
#pragma unroll
      for (int n = 0; n < 4; ++n) {
        int kr = n * 16 + r;
        bf16x8 kf = *reinterpret_cast<const bf16x8*>(
            KsB + ((kr << 8) | ((t * 64 + g * 16) ^ ((kr & 7) << 4))));
        s[n] = __builtin_amdgcn_mfma_f32_16x16x32_bf16(qf[t], kf, s[n], 0, 0, 0);
      }
    }
    __builtin_amdgcn_s_setprio(0);

    // fixed-max softmax: p = exp(S*sc - 20); row sums come from MFMA-ones in PV
#pragma unroll
    for (int n = 0; n < 4; ++n) {
#pragma unroll
      for (int j = 0; j < 4; ++j) {
        float p = __expf(s[n][j] * sc - 20.0f);
        int ql = qrow + g * 4 + j;
        int col = n * 16 + r;
        *reinterpret_cast<u16*>(PsB + ((ql << 7) | ((col << 1) ^ ((ql & 7) << 4)))) = f2b(p);
      }
    }

    // O += P V  (A = P from LDS, B = VT from LDS); lacc += P * ones (row sums)
    __builtin_amdgcn_s_setprio(1);
#pragma unroll
    for (int t = 0; t < 2; ++t) {
      int pr = qrow + r;
      bf16x8 pf = *reinterpret_cast<const bf16x8*>(
          PsB + ((pr << 7) | ((t * 64 + g * 16) ^ ((pr & 7) << 4))));
      lacc = __builtin_amdgcn_mfma_f32_16x16x32_bf16(pf, vone, lacc, 0, 0, 0);
#pragma unroll
      for (int n = 0; n < 8; ++n) {
        int vr = n * 16 + r;
        bf16x8 vf = *reinterpret_cast<const bf16x8*>(
            VsB + ((vr << 7) | ((t * 64 + g * 16) ^ ((vr & 7) << 4))));
        oacc[n] = __builtin_amdgcn_mfma_f32_16x16x32_bf16(pf, vf, oacc[n], 0, 0, 0);
      }
    }
    __builtin_amdgcn_s_setprio(0);

    // end of iter: next tile's loads complete; all waves done with buf[cur]
    asm volatile("s_waitcnt vmcnt(0)" ::: "memory");
    __builtin_amdgcn_s_barrier();
  }

  // epilogue: O /= l, write [B, L, H*D]
  {
    f32x4 inv;
#pragma unroll
    for (int j = 0; j < 4; ++j) inv[j] = 1.0f / lacc[j];
#pragma unroll
    for (int n = 0; n < 8; ++n)
#pragma unroll
      for (int j = 0; j < 4; ++j) {
        int ql = qrow + g * 4 + j;
        int col = n * 16 + r;
        Og[((long)(b * L_) + q0 + ql) * DIM_ + h * D_ + col] = f2b(oacc[n][j] * inv[j]);
      }
  }
}

extern "C" void kernel_launch(void* const* d_in, const int* in_sizes, int n_in,
                              void* d_out, int out_size, void* d_ws, size_t ws_size,
                              hipStream_t stream) {
  const float* x    = (const float*)d_in[0];
  const float* pe   = (const float*)d_in[1];
  const float* qkvw = (const float*)d_in[2];
  const float* qsc  = (const float*)d_in[3];
  const float* ksc  = (const float*)d_in[4];
  const float* pw   = (const float*)d_in[5];
  const float* pb   = (const float*)d_in[6];
  float* out = (float*)d_out;

  u16* ws_x   = (u16*)d_ws;                   //  8,388,608 elems
  u16* ws_w1  = ws_x   + (size_t)ML_ * DIM_;  // 12,582,912
  u16* ws_w2  = ws_w1  + (size_t)E3_ * DIM_;  //  4,194,304
  u16* ws_qkv = ws_w2  + (size_t)DIM_ * DIM_; // 25,165,824
  u16* ws_q   = ws_qkv + (size_t)ML_ * E3_;   //  8,388,608
  u16* ws_k   = ws_q   + (size_t)ML_ * DIM_;
  u16* ws_vt  = ws_k   + (size_t)ML_ * DIM_;
  u16* ws_o   = ws_vt  + (size_t)ML_ * DIM_;  // total 160 MiB

  cvt_kernel<<<2048, 256, 0, stream>>>(x, ws_x, ML_ * DIM_ / 4);
  cvt_kernel<<<2048, 256, 0, stream>>>(qkvw, ws_w1, E3_ * DIM_ / 4);
  cvt_kernel<<<2048, 256, 0, stream>>>(pw, ws_w2, DIM_ * DIM_ / 4);

  gemm256_bt<<<dim3(E3_ / 256, ML_ / 256), 512, 0, stream>>>(
      ws_x, ws_w1, ws_qkv, ML_, E3_, DIM_);
  normrope_kernel<<<(B_ * L_ * H_) / 4, 256, 0, stream>>>(ws_qkv, pe, qsc, ksc, ws_q, ws_k);
  vtrans_kernel<<<B_ * H_ * (L_ / 64), 256, 0, stream>>>(ws_qkv, ws_vt);
  flash_kernel<<<dim3(L_ / 128, B_ * H_), 512, 0, stream>>>(ws_q, ws_k, ws_vt, ws_o);
  gemm_bt<1><<<dim3(DIM_ / 128, ML_ / 128), 256, 0, stream>>>(
      ws_o, ws_w2, nullptr, out, pb, ML_, DIM_, DIM_);
}